// Round 7
// baseline (1867.676 us; speedup 1.0000x reference)
//
#include <hip/hip_runtime.h>
#include <math.h>

#define B_ 64
#define T_ 1024
#define I_ 128
#define H_ 512

typedef _Float16 h2_t __attribute__((ext_vector_type(2)));
union U32H2 { unsigned u; h2_t h; };

__device__ __forceinline__ float fdot2u(unsigned a, unsigned b, float c) {
    U32H2 ua, ub; ua.u = a; ub.u = b;
    return __builtin_amdgcn_fdot2(ua.h, ub.h, c, false);
}
__device__ __forceinline__ unsigned packh2(float x, float y) {
    U32H2 r; r.h.x = (_Float16)x; r.h.y = (_Float16)y; return r.u;
}

// ---------------- prep: pack fp16 weight layouts ------------------------------
// rnn map (512 thr): w=tid>>6 (wave), l=tid&63, u=l&15, c=(l>>4)&3 (k-slice),
// g=w*16+u (output quad: rows 4g..4g+3). Thread covers k-words c*64..c*64+63:
// words 0..51 of slice in REG, 52..63 in LDS.
// wpack u32[((j*13+q)*512 + tid)*4 + r4] = half2 W[4g+j][2*(c*64+4q+r4)..+1]
// wldsg u32[((c*12+m)*128 + g)*4 + r]   = half2 W[4g+r][2*(c*64+52+m)..+1]
// wih2[(i2<<9)+h] = half2 Wih[h][2i2..+1];  biasv[h] = b_ih[h]+b_hh[h]
__global__ void prep(const float* __restrict__ wih, const float* __restrict__ whh,
                     const float* __restrict__ bih, const float* __restrict__ bhh,
                     unsigned* __restrict__ wpack, unsigned* __restrict__ wldsg,
                     unsigned* __restrict__ wih2, float* __restrict__ biasv) {
    int e = blockIdx.x * 256 + threadIdx.x;
    if (e < 106496) {                    // 512 thr * 52 uint4 * 4
        int r4 = e & 3;
        int u4 = e >> 2;
        int tid = u4 & 511;
        int jq = u4 >> 9;                // 0..51
        int j = jq / 13, q = jq % 13;
        int c = (tid >> 4) & 3;
        int g = ((tid >> 6) << 4) + (tid & 15);
        int row = (g << 2) + j;
        int word = (c << 6) + (q << 2) + r4;
        wpack[e] = packh2(whh[row * H_ + 2 * word], whh[row * H_ + 2 * word + 1]);
    }
    if (e < 24576) {                     // 4c * 12m * 128g * 4r
        int r = e & 3;
        int uu = e >> 2;
        int g = uu & 127;
        int cm = uu >> 7;                // 0..47
        int c = cm / 12, m = cm % 12;
        int row = (g << 2) + r;
        int word = (c << 6) + 52 + m;
        wldsg[e] = packh2(whh[row * H_ + 2 * word], whh[row * H_ + 2 * word + 1]);
    }
    if (e < 64 * 512) {
        int i2 = e >> 9, h = e & 511;
        wih2[e] = packh2(wih[h * I_ + (i2 << 1)], wih[h * I_ + (i2 << 1) + 1]);
    }
    if (e < H_) biasv[e] = bih[e] + bhh[e];
}

// ---------------- xp = x @ W_ih^T + biases, fp16 [B][T][H] (unchanged) --------
__global__ __launch_bounds__(512, 2) void xp_gemm(
    const float* __restrict__ x, const unsigned* __restrict__ wih2,
    const float* __restrict__ biasv, _Float16* __restrict__ xph) {
    __shared__ unsigned w2[64 * 512];
    __shared__ unsigned x2[32 * 64];
    const int tid = threadIdx.x, b = blockIdx.x, t0 = blockIdx.y * 32;

    #pragma unroll
    for (int q = 0; q < 64; ++q) w2[tid + (q << 9)] = wih2[tid + (q << 9)];
    #pragma unroll
    for (int q = 0; q < 4; ++q) {
        int idx = tid * 4 + q;
        int t = idx >> 6, i2 = idx & 63;
        const float2 xv = *(const float2*)(x + ((size_t)b * T_ + t0 + t) * I_ + (i2 << 1));
        x2[idx] = packh2(xv.x, xv.y);
    }
    __syncthreads();
    const float bias = biasv[tid];
    for (int t = 0; t < 32; ++t) {
        float acc = bias;
        #pragma unroll
        for (int i2 = 0; i2 < 64; ++i2)
            acc = fdot2u(x2[(t << 6) + i2], w2[(i2 << 9) + tid], acc);
        xph[((size_t)b * T_ + t0 + t) * H_ + tid] = (_Float16)acc;
    }
}

// ---------------- serial recurrence: one WG (512 thr, 8 waves) per chain ------
// k-slice c lives in LANE bits 4-5 -> cross-slice reduce = 2 shfl_xor,
// no part[] buffer, no reduce phase, ONE barrier per step (h double-buffered).
// Weights: 208 h2-words in registers + 48 from LDS (96 KB) per thread.
__global__ __launch_bounds__(512) void rnn_fused(
    const unsigned* __restrict__ xp2,    // [B][T][256] half2 words
    const unsigned* __restrict__ wpack,
    const unsigned* __restrict__ wldsg,
    const float* __restrict__ fcw, const float* __restrict__ fcb,
    float* __restrict__ out)
{
    __shared__ __align__(16) unsigned wlds[24576];   // 96 KB weights (LDS part)
    __shared__ __align__(16) unsigned h2buf[512];    // 2 x 256 h2-words
    __shared__ float wsum[4];

    const int tid = threadIdx.x;
    const int b = blockIdx.x;
    const int l = tid & 63;
    const int w = tid >> 6;
    const int u = l & 15;
    const int c = (l >> 4) & 3;
    const int g = (w << 4) + u;          // output quad 4g..4g+3

    {   // stage LDS weights: 6144 uint4, 12 per thread, coalesced
        const uint4* src = (const uint4*)wldsg;
        uint4* dst = (uint4*)wlds;
        #pragma unroll
        for (int q = 0; q < 12; ++q) dst[tid + (q << 9)] = src[tid + (q << 9)];
    }
    uint4 wr[4][13];                     // 208 h2-words of weights
    {
        const uint4* wp4 = ((const uint4*)wpack) + tid;
        #pragma unroll
        for (int j = 0; j < 4; ++j)
            #pragma unroll
            for (int q = 0; q < 13; ++q)
                wr[j][q] = wp4[(j * 13 + q) << 9];
    }
    if (tid < 256) h2buf[tid] = 0u;      // h(0) = 0 in buffer 0
    __syncthreads();

    const unsigned* xpb = xp2 + (size_t)b * T_ * 256;
    const uint4* wq = ((const uint4*)wlds) + c * 1536 + g;  // + m*128, imm-safe

    for (int t = 0; t < T_; ++t) {
        const int p = t & 1;
        const uint4* hv = ((const uint4*)(h2buf + (p << 8))) + (c << 4);
        const uint2 xpw = *(const uint2*)(xpb + t * 256 + 2 * g);

        float a0 = 0.f, a1 = 0.f, a2 = 0.f, a3 = 0.f;
        // register weights: 13 b128 h-reads, 208 dots
        #pragma unroll
        for (int q = 0; q < 13; ++q) {
            const uint4 hh = hv[q];
            a0 = fdot2u(wr[0][q].x, hh.x, a0); a1 = fdot2u(wr[1][q].x, hh.x, a1);
            a2 = fdot2u(wr[2][q].x, hh.x, a2); a3 = fdot2u(wr[3][q].x, hh.x, a3);
            a0 = fdot2u(wr[0][q].y, hh.y, a0); a1 = fdot2u(wr[1][q].y, hh.y, a1);
            a2 = fdot2u(wr[2][q].y, hh.y, a2); a3 = fdot2u(wr[3][q].y, hh.y, a3);
            a0 = fdot2u(wr[0][q].z, hh.z, a0); a1 = fdot2u(wr[1][q].z, hh.z, a1);
            a2 = fdot2u(wr[2][q].z, hh.z, a2); a3 = fdot2u(wr[3][q].z, hh.z, a3);
            a0 = fdot2u(wr[0][q].w, hh.w, a0); a1 = fdot2u(wr[1][q].w, hh.w, a1);
            a2 = fdot2u(wr[2][q].w, hh.w, a2); a3 = fdot2u(wr[3][q].w, hh.w, a3);
        }
        // LDS weights: 3 b128 h-reads + 12 coalesced b128 weight reads, 48 dots
        #pragma unroll
        for (int s = 0; s < 3; ++s) {
            const uint4 hh = hv[13 + s];
            {   const uint4 w0 = wq[(4 * s + 0) * 128];
                a0 = fdot2u(w0.x, hh.x, a0); a1 = fdot2u(w0.y, hh.x, a1);
                a2 = fdot2u(w0.z, hh.x, a2); a3 = fdot2u(w0.w, hh.x, a3); }
            {   const uint4 w1 = wq[(4 * s + 1) * 128];
                a0 = fdot2u(w1.x, hh.y, a0); a1 = fdot2u(w1.y, hh.y, a1);
                a2 = fdot2u(w1.z, hh.y, a2); a3 = fdot2u(w1.w, hh.y, a3); }
            {   const uint4 w2v = wq[(4 * s + 2) * 128];
                a0 = fdot2u(w2v.x, hh.z, a0); a1 = fdot2u(w2v.y, hh.z, a1);
                a2 = fdot2u(w2v.z, hh.z, a2); a3 = fdot2u(w2v.w, hh.z, a3); }
            {   const uint4 w3 = wq[(4 * s + 3) * 128];
                a0 = fdot2u(w3.x, hh.w, a0); a1 = fdot2u(w3.y, hh.w, a1);
                a2 = fdot2u(w3.z, hh.w, a2); a3 = fdot2u(w3.w, hh.w, a3); }
        }
        // cross-slice reduce: butterfly over lane bits 4,5 (c)
        a0 += __shfl_xor(a0, 16); a0 += __shfl_xor(a0, 32);
        a1 += __shfl_xor(a1, 16); a1 += __shfl_xor(a1, 32);
        a2 += __shfl_xor(a2, 16); a2 += __shfl_xor(a2, 32);
        a3 += __shfl_xor(a3, 16); a3 += __shfl_xor(a3, 32);

        // tail on all lanes (redundant x4), lanes<16 write h(t+1)
        U32H2 x0, x1; x0.u = xpw.x; x1.u = xpw.y;
        const float p0 = (float)x0.h.x + a0;
        const float p1 = (float)x0.h.y + a1;
        const float p2f = (float)x1.h.x + a2;
        const float p3 = (float)x1.h.y + a3;
        const float h0 = 1.f - 2.f * __builtin_amdgcn_rcpf(__expf(2.f * p0) + 1.f);
        const float h1 = 1.f - 2.f * __builtin_amdgcn_rcpf(__expf(2.f * p1) + 1.f);
        const float h2v = 1.f - 2.f * __builtin_amdgcn_rcpf(__expf(2.f * p2f) + 1.f);
        const float h3 = 1.f - 2.f * __builtin_amdgcn_rcpf(__expf(2.f * p3) + 1.f);
        if (l < 16) {
            uint2 hw; hw.x = packh2(h0, h1); hw.y = packh2(h2v, h3);
            *(uint2*)(h2buf + ((p ^ 1) << 8) + 2 * g) = hw;
        }
        __syncthreads();                 // single barrier per step
    }

    // head: final h is in buffer 0 (T even)
    float pr = 0.f;
    if (tid < 256) {
        U32H2 hu; hu.u = h2buf[tid];
        pr = (float)hu.h.x * fcw[tid << 1] + (float)hu.h.y * fcw[(tid << 1) + 1];
    }
    #pragma unroll
    for (int off = 32; off >= 1; off >>= 1) pr += __shfl_down(pr, off, 64);
    if ((tid & 63) == 0 && tid < 256) wsum[tid >> 6] = pr;
    __syncthreads();
    if (tid == 0) out[b] = wsum[0] + wsum[1] + wsum[2] + wsum[3] + fcb[0];
}

extern "C" void kernel_launch(void* const* d_in, const int* in_sizes, int n_in,
                              void* d_out, int out_size, void* d_ws, size_t ws_size,
                              hipStream_t stream) {
    const float* x   = (const float*)d_in[0];
    const float* wih = (const float*)d_in[1];
    const float* whh = (const float*)d_in[2];
    const float* bih = (const float*)d_in[3];
    const float* bhh = (const float*)d_in[4];
    const float* fcw = (const float*)d_in[5];
    const float* fcb = (const float*)d_in[6];
    float* out = (float*)d_out;

    // workspace (u32 units): xp2 | wpack | wldsg | wih2 | biasv  (~64.6 MiB)
    unsigned* xp2   = (unsigned*)d_ws;            // 64*1024*256 = 16,777,216
    unsigned* wpack = xp2 + 16777216;             // 106,496
    unsigned* wldsg = wpack + 106496;             // 24,576
    unsigned* wih2  = wldsg + 24576;              // 32,768
    float*    biasv = (float*)(wih2 + 32768);     // 512

    hipLaunchKernelGGL(prep, dim3(416), dim3(256), 0, stream,
                       wih, whh, bih, bhh, wpack, wldsg, wih2, biasv);
    hipLaunchKernelGGL(xp_gemm, dim3(B_, 32), dim3(512), 0, stream,
                       x, wih2, biasv, (_Float16*)xp2);
    hipLaunchKernelGGL(rnn_fused, dim3(B_), dim3(512), 0, stream,
                       xp2, wpack, wldsg, fcw, fcb, out);
}